// Round 1
// baseline (606.678 us; speedup 1.0000x reference)
//
#include <hip/hip_runtime.h>
#include <math.h>

#define LN2F 0.69314718055994531f

typedef _Float16 v8hf __attribute__((ext_vector_type(8)));
typedef _Float16 v2hf __attribute__((ext_vector_type(2)));
typedef float    v4f  __attribute__((ext_vector_type(4)));

// fast shifted-softplus via v_exp_f32/v_log_f32 (~10 VALU instr vs ~50 libm).
__device__ __forceinline__ float ssp_fast(float x) {
    float e = __expf(-fabsf(x));
    return fmaxf(x, 0.f) + __logf(1.f + e) - LN2F;
}

// ---------------------------------------------------------------------------
// Prep: weights -> f16, MFMA-B-fragment order.
// ---------------------------------------------------------------------------
__global__ __launch_bounds__(256)
void prep_kernel(const float* __restrict__ w1, const float* __restrict__ w2,
                 const float* __restrict__ l1w, const float* __restrict__ l2w,
                 const float* __restrict__ lw,
                 _Float16* __restrict__ w1f, _Float16* __restrict__ w2f,
                 _Float16* __restrict__ l1f, _Float16* __restrict__ l2f,
                 _Float16* __restrict__ lwf)
{
    int idx = blockIdx.x * 256 + threadIdx.x;
    if (idx < 8192) {  // w1f
        int i = idx & 7, lane = (idx >> 3) & 63, ks = (idx >> 9) & 1, nt = idx >> 10;
        int r = nt * 16 + (lane & 15);
        int k = ks * 32 + (lane >> 4) * 8 + i;
        w1f[idx] = (k < 50) ? (_Float16)w1[r * 50 + k] : (_Float16)0.f;
        return;
    }
    int o = idx - 8192;
    if (o >= 4 * 16384) return;
    int which = o >> 14;
    int p = o & 16383;
    int i = p & 7, lane = (p >> 3) & 63, ks = (p >> 9) & 3, nt = p >> 11;
    int r = nt * 16 + (lane & 15);
    int k = ks * 32 + (lane >> 4) * 8 + i;
    const float* src = (which == 0) ? w2 : (which == 1) ? l1w : (which == 2) ? l2w : lw;
    _Float16* dst   = (which == 0) ? w2f : (which == 1) ? l1f : (which == 2) ? l2f : lwf;
    dst[p] = (_Float16)src[r * 128 + k];
}

// ---------------------------------------------------------------------------
// h = X @ W^T (no bias/act). f16 MFMA, B-frags from global. 4 waves x 16 rows.
// ---------------------------------------------------------------------------
__global__ __launch_bounds__(256)
void h_gemm_kernel(const float* __restrict__ X, const _Float16* __restrict__ Wf,
                   float* __restrict__ Y, int M)
{
    const int tid = threadIdx.x, lane = tid & 63, wv = tid >> 6;
    const int l15 = lane & 15, quad = lane >> 4;
    const int mb = blockIdx.x * 64 + wv * 16;

    const int mA = (mb + l15 < M) ? (mb + l15) : (M - 1);
    v8hf a[4];
    #pragma unroll
    for (int ks = 0; ks < 4; ++ks) {
        const float4* xp = (const float4*)&X[(size_t)mA * 128 + ks * 32 + quad * 8];
        float4 x0 = xp[0], x1 = xp[1];
        v8hf t = {(_Float16)x0.x, (_Float16)x0.y, (_Float16)x0.z, (_Float16)x0.w,
                  (_Float16)x1.x, (_Float16)x1.y, (_Float16)x1.z, (_Float16)x1.w};
        a[ks] = t;
    }
    #pragma unroll
    for (int nt = 0; nt < 8; ++nt) {
        v4f acc = {0.f, 0.f, 0.f, 0.f};
        #pragma unroll
        for (int ks = 0; ks < 4; ++ks) {
            const v8hf b = *(const v8hf*)&Wf[((nt * 4 + ks) * 64 + lane) * 8];
            acc = __builtin_amdgcn_mfma_f32_16x16x32_f16(a[ks], b, acc, 0, 0, 0);
        }
        const int col = nt * 16 + l15;
        #pragma unroll
        for (int r = 0; r < 4; ++r) {
            int row = mb + quad * 4 + r;
            if (row < M) Y[(size_t)row * 128 + col] = acc[r];
        }
    }
}

// ---------------------------------------------------------------------------
// Fused tail: out = ssp(agg @ l2^T + l2b) @ lw^T + lb.
// ---------------------------------------------------------------------------
__global__ __launch_bounds__(256)
void fused_out_kernel(const float* __restrict__ agg, const _Float16* __restrict__ l2f,
                      const float* __restrict__ l2b, const _Float16* __restrict__ lwf,
                      const float* __restrict__ lb, float* __restrict__ out, int M)
{
    __shared__ __align__(16) _Float16 Sh[64 * 138];
    const int tid = threadIdx.x, lane = tid & 63, wv = tid >> 6;
    const int l15 = lane & 15, quad = lane >> 4;
    const int m0 = wv * 16;
    const int gbase = blockIdx.x * 64;

    const int mA = (gbase + m0 + l15 < M) ? (gbase + m0 + l15) : (M - 1);
    v8hf a[4];
    #pragma unroll
    for (int ks = 0; ks < 4; ++ks) {
        const float4* xp = (const float4*)&agg[(size_t)mA * 128 + ks * 32 + quad * 8];
        float4 x0 = xp[0], x1 = xp[1];
        v8hf t = {(_Float16)x0.x, (_Float16)x0.y, (_Float16)x0.z, (_Float16)x0.w,
                  (_Float16)x1.x, (_Float16)x1.y, (_Float16)x1.z, (_Float16)x1.w};
        a[ks] = t;
    }
    #pragma unroll
    for (int nt = 0; nt < 8; ++nt) {
        v4f acc = {0.f, 0.f, 0.f, 0.f};
        #pragma unroll
        for (int ks = 0; ks < 4; ++ks) {
            const v8hf b = *(const v8hf*)&l2f[((nt * 4 + ks) * 64 + lane) * 8];
            acc = __builtin_amdgcn_mfma_f32_16x16x32_f16(a[ks], b, acc, 0, 0, 0);
        }
        const float bj = l2b[nt * 16 + l15];
        #pragma unroll
        for (int r = 0; r < 4; ++r)
            Sh[(m0 + quad * 4 + r) * 138 + nt * 16 + l15] =
                (_Float16)ssp_fast(acc[r] + bj);
    }
    v8hf ua[4];
    #pragma unroll
    for (int ks = 0; ks < 4; ++ks)
        ua[ks] = *(const v8hf*)&Sh[(m0 + l15) * 138 + ks * 32 + quad * 8];

    #pragma unroll
    for (int nt = 0; nt < 8; ++nt) {
        v4f acc = {0.f, 0.f, 0.f, 0.f};
        #pragma unroll
        for (int ks = 0; ks < 4; ++ks) {
            const v8hf b = *(const v8hf*)&lwf[((nt * 4 + ks) * 64 + lane) * 8];
            acc = __builtin_amdgcn_mfma_f32_16x16x32_f16(ua[ks], b, acc, 0, 0, 0);
        }
        const int col = nt * 16 + l15;
        const float bj = lb[col];
        #pragma unroll
        for (int r = 0; r < 4; ++r) {
            int row = gbase + m0 + quad * 4 + r;
            if (row < M) out[(size_t)row * 128 + col] = acc[r] + bj;
        }
    }
}

// ---------------------------------------------------------------------------
// Fused edge kernel. MODE 0: legacy atomic scatter into agg (fallback when
// workspace is too small for msg). MODE 1: store msg = W*C*h[src] as f32
// (bit-identical math to the atomic path). MODE 2: store msg as f16.
// The 82M device-scope f32 atomics of MODE 0 resolve memory-side (per-XCD L2s
// non-coherent) at ~0.95 TB/s effective -- that WAS the 345us bottleneck.
// MODE 1/2 replace them with coalesced 64B plain stores.
// ---------------------------------------------------------------------------
template<int MODE>
__global__ __launch_bounds__(256, 5)
void edge_kernel(const float* __restrict__ attr,  // E x 50
                 const float* __restrict__ ew,    // E
                 const int* __restrict__ srcI,
                 const int* __restrict__ dstI,
                 const _Float16* __restrict__ w1f,
                 const _Float16* __restrict__ w2f,
                 const float* __restrict__ b1,
                 const float* __restrict__ b2,
                 const float* __restrict__ h,     // N x 128
                 float* __restrict__ agg,         // N x 128 (MODE 0 only)
                 float* __restrict__ msg32,       // E x 128 (MODE 1)
                 _Float16* __restrict__ msg16,    // E x 128 (MODE 2)
                 int E)
{
    __shared__ __align__(16) _Float16 Af[64 * 64];   // A-fragment-packed attr
    __shared__ __align__(16) _Float16 Uh[64 * 138];

    const int tid = threadIdx.x;
    const int e_base = blockIdx.x * 64;
    const int lane = tid & 63, wv = tid >> 6;
    const int m0 = wv * 16, l15 = lane & 15, quad = lane >> 4;

    // ---- per-lane edge metadata (direct global; 16-lane groups share -> L1) ----
    float cC[4]; const float* hrow[4]; float* arow[4]; bool val[4]; int eidx[4];
    #pragma unroll
    for (int r = 0; r < 4; ++r) {
        int eg = e_base + m0 + quad * 4 + r;
        val[r] = eg < E;
        eidx[r] = eg;
        int e = val[r] ? eg : (E - 1);
        cC[r] = 0.5f * (__cosf(ew[e] * 0.31415926535897932f) + 1.f);
        hrow[r] = h + (size_t)srcI[e] * 128;
        if constexpr (MODE == 0) arow[r] = agg + (size_t)dstI[e] * 128;
    }

    // ---- stage attr -> LDS in A-fragment order ----
    for (int idx = tid; idx < 4096; idx += 256) {
        int r = idx >> 6, g = idx & 63;
        int e = e_base + r;
        float v = (g < 50 && e < E) ? attr[(size_t)e * 50 + g] : 0.f;
        Af[((((r >> 4) * 2 + (g >> 5)) * 64) + (((g & 31) >> 3) * 16) + (r & 15)) * 8
           + (g & 7)] = (_Float16)v;
    }
    __syncthreads();

    // ---- h-gather prefetch: latency hides behind both MFMA stages ----
    float hv[8][4];
    #pragma unroll
    for (int nt = 0; nt < 8; ++nt)
        #pragma unroll
        for (int r = 0; r < 4; ++r)
            hv[nt][r] = hrow[r][nt * 16 + l15];

    // ---- stage 1: u = ssp(attr @ W1^T + b1) -> Uh (wave-private rows) ----
    const v8hf a0 = *(const v8hf*)&Af[((wv * 2 + 0) * 64 + lane) * 8];
    const v8hf a1 = *(const v8hf*)&Af[((wv * 2 + 1) * 64 + lane) * 8];
    #pragma unroll
    for (int nt = 0; nt < 8; ++nt) {
        v4f acc = {0.f, 0.f, 0.f, 0.f};
        const v8hf bA = *(const v8hf*)&w1f[((nt * 2 + 0) * 64 + lane) * 8];
        const v8hf bB = *(const v8hf*)&w1f[((nt * 2 + 1) * 64 + lane) * 8];
        acc = __builtin_amdgcn_mfma_f32_16x16x32_f16(a0, bA, acc, 0, 0, 0);
        acc = __builtin_amdgcn_mfma_f32_16x16x32_f16(a1, bB, acc, 0, 0, 0);
        const float bj = b1[nt * 16 + l15];
        #pragma unroll
        for (int r = 0; r < 4; ++r)
            Uh[(m0 + quad * 4 + r) * 138 + nt * 16 + l15] =
                (_Float16)ssp_fast(acc[r] + bj);
    }

    // ---- stage 2 + D-layout epilogue (wave-private LDS rows) ----
    v8hf ua[4];
    #pragma unroll
    for (int ks = 0; ks < 4; ++ks)
        ua[ks] = *(const v8hf*)&Uh[(m0 + l15) * 138 + ks * 32 + quad * 8];

    #pragma unroll
    for (int nt = 0; nt < 8; ++nt) {
        v4f acc = {0.f, 0.f, 0.f, 0.f};
        #pragma unroll
        for (int ks = 0; ks < 4; ++ks) {
            const v8hf b = *(const v8hf*)&w2f[((nt * 4 + ks) * 64 + lane) * 8];
            acc = __builtin_amdgcn_mfma_f32_16x16x32_f16(ua[ks], b, acc, 0, 0, 0);
        }
        const int col = nt * 16 + l15;
        const float bj = b2[col];
        #pragma unroll
        for (int r = 0; r < 4; ++r) {
            if (val[r]) {
                float m = (acc[r] + bj) * cC[r] * hv[nt][r];
                if constexpr (MODE == 0)
                    atomicAdd(&arow[r][col], m);
                else if constexpr (MODE == 1)
                    msg32[(size_t)eidx[r] * 128 + col] = m;
                else
                    msg16[(size_t)eidx[r] * 128 + col] = (_Float16)m;
            }
        }
    }
}

// ---------------------------------------------------------------------------
// CSR build: histogram of dst -> in-place exclusive scan -> scatter edge ids.
// ---------------------------------------------------------------------------
__global__ __launch_bounds__(256)
void hist_kernel(const int* __restrict__ dst, int* __restrict__ counts, int E)
{
    int i = blockIdx.x * 256 + threadIdx.x;
    const int stride = gridDim.x * 256;
    for (; i < E; i += stride) atomicAdd(&counts[dst[i]], 1);
}

// Per-block (1024 elems) in-place exclusive scan; block totals -> bsum[b].
__global__ __launch_bounds__(256)
void scan1_kernel(int* __restrict__ data, int* __restrict__ bsum, int N)
{
    __shared__ int wsum[4];
    const int t = threadIdx.x, lane = t & 63, wv = t >> 6;
    const int base = blockIdx.x * 1024 + t * 4;
    int v0 = 0, v1 = 0, v2 = 0, v3 = 0;
    if (base + 0 < N) v0 = data[base + 0];
    if (base + 1 < N) v1 = data[base + 1];
    if (base + 2 < N) v2 = data[base + 2];
    if (base + 3 < N) v3 = data[base + 3];
    const int s = v0 + v1 + v2 + v3;
    int sc = s;
    #pragma unroll
    for (int d = 1; d < 64; d <<= 1) {
        int o = __shfl_up(sc, d);
        if (lane >= d) sc += o;
    }
    if (lane == 63) wsum[wv] = sc;
    __syncthreads();
    int wo = 0;
    for (int j = 0; j < wv; ++j) wo += wsum[j];
    int run = wo + (sc - s);   // exclusive prefix of this thread's 4 elems
    if (base + 0 < N) data[base + 0] = run; run += v0;
    if (base + 1 < N) data[base + 1] = run; run += v1;
    if (base + 2 < N) data[base + 2] = run; run += v2;
    if (base + 3 < N) data[base + 3] = run; run += v3;
    if (t == 255) bsum[blockIdx.x] = wo + sc;
}

// Add prefix of raw block totals (tiny NB -> each block sums bsum[0..b-1]),
// mirror into cursor array, set offs[N]=E.
__global__ __launch_bounds__(256)
void scan2_kernel(int* __restrict__ offs, const int* __restrict__ bsum,
                  int* __restrict__ cur, int N, int E)
{
    int add = 0;
    for (int j = 0; j < (int)blockIdx.x; ++j) add += bsum[j];
    const int base = blockIdx.x * 1024 + threadIdx.x * 4;
    #pragma unroll
    for (int r = 0; r < 4; ++r) {
        int i = base + r;
        if (i < N) { int o = offs[i] + add; offs[i] = o; cur[i] = o; }
    }
    if (blockIdx.x == 0 && threadIdx.x == 0) offs[N] = E;
}

__global__ __launch_bounds__(256)
void scatter_kernel(const int* __restrict__ dst, int* __restrict__ cur,
                    int* __restrict__ perm, int E)
{
    int i = blockIdx.x * 256 + threadIdx.x;
    const int stride = gridDim.x * 256;
    for (; i < E; i += stride) {
        int p = atomicAdd(&cur[dst[i]], 1);
        perm[p] = i;
    }
}

// ---------------------------------------------------------------------------
// Gather: one wave per dst node; lane owns 2 cols. Sums the node's msg rows
// (512B/256B coalesced, full-line-utilized) -> plain store of agg row.
// Writes every row incl. degree-0 -> no agg memset needed.
// ---------------------------------------------------------------------------
template<int MODE>
__global__ __launch_bounds__(256)
void gather_kernel(const float* __restrict__ msg32, const _Float16* __restrict__ msg16,
                   const int* __restrict__ offs, const int* __restrict__ perm,
                   float* __restrict__ agg, int N)
{
    const int lane = threadIdx.x & 63, wv = threadIdx.x >> 6;
    const int n = blockIdx.x * 4 + wv;
    if (n >= N) return;
    const int s = offs[n], e = offs[n + 1];
    float ax0 = 0.f, ay0 = 0.f, ax1 = 0.f, ay1 = 0.f;
    for (int k0 = s; k0 < e; k0 += 64) {
        const int pv = (k0 + lane < e) ? perm[k0 + lane] : 0;
        const int cnt = min(64, e - k0);
        int k = 0;
        for (; k + 1 < cnt; k += 2) {    // 2-deep unroll: independent loads
            const int e0 = __shfl(pv, k);
            const int e1 = __shfl(pv, k + 1);
            if constexpr (MODE == 1) {
                const float2 m0 = *(const float2*)&msg32[(size_t)e0 * 128 + lane * 2];
                const float2 m1 = *(const float2*)&msg32[(size_t)e1 * 128 + lane * 2];
                ax0 += m0.x; ay0 += m0.y; ax1 += m1.x; ay1 += m1.y;
            } else {
                const v2hf m0 = *(const v2hf*)&msg16[(size_t)e0 * 128 + lane * 2];
                const v2hf m1 = *(const v2hf*)&msg16[(size_t)e1 * 128 + lane * 2];
                ax0 += (float)m0[0]; ay0 += (float)m0[1];
                ax1 += (float)m1[0]; ay1 += (float)m1[1];
            }
        }
        if (k < cnt) {
            const int e0 = __shfl(pv, k);
            if constexpr (MODE == 1) {
                const float2 m0 = *(const float2*)&msg32[(size_t)e0 * 128 + lane * 2];
                ax0 += m0.x; ay0 += m0.y;
            } else {
                const v2hf m0 = *(const v2hf*)&msg16[(size_t)e0 * 128 + lane * 2];
                ax0 += (float)m0[0]; ay0 += (float)m0[1];
            }
        }
    }
    float2 o; o.x = ax0 + ax1; o.y = ay0 + ay1;
    *(float2*)&agg[(size_t)n * 128 + lane * 2] = o;
}

extern "C" void kernel_launch(void* const* d_in, const int* in_sizes, int n_in,
                              void* d_out, int out_size, void* d_ws, size_t ws_size,
                              hipStream_t stream)
{
    const float* x   = (const float*)d_in[0];
    const int*   ei  = (const int*)  d_in[1];
    const float* ew  = (const float*)d_in[2];
    const float* ea  = (const float*)d_in[3];
    const float* w1  = (const float*)d_in[4];
    const float* b1  = (const float*)d_in[5];
    const float* w2  = (const float*)d_in[6];
    const float* b2  = (const float*)d_in[7];
    const float* l1w = (const float*)d_in[8];
    const float* l2w = (const float*)d_in[9];
    const float* l2b = (const float*)d_in[10];
    const float* lw  = (const float*)d_in[11];
    const float* lb  = (const float*)d_in[12];

    const int N = in_sizes[0] / 128;   // 40000
    const int E = in_sizes[2];         // 640000
    const int NB = (N + 1023) / 1024;

    char* base = (char*)d_ws;
    size_t off = 0;
    auto take = [&](size_t bytes) -> char* {
        char* r = base + off;
        off = (off + bytes + 255) & ~(size_t)255;
        return r;
    };
    float*    hbuf = (float*)   take((size_t)N * 128 * 4);
    float*    agg  = (float*)   take((size_t)N * 128 * 4);
    _Float16* w1f  = (_Float16*)take(8192 * 2);
    _Float16* w2f  = (_Float16*)take(16384 * 2);
    _Float16* l1f  = (_Float16*)take(16384 * 2);
    _Float16* l2f  = (_Float16*)take(16384 * 2);
    _Float16* lwf  = (_Float16*)take(16384 * 2);
    int*      offs = (int*)     take((size_t)(N + 1) * 4);
    int*      cur  = (int*)     take((size_t)N * 4);
    int*      bsum = (int*)     take((size_t)NB * 4);
    int*      perm = (int*)     take((size_t)E * 4);
    const size_t base_bytes = off;

    // msg fits? prefer f32 (bit-identical to atomic path), then f16, then fallback.
    int mode;
    if      (ws_size >= base_bytes + (size_t)E * 128 * 4) mode = 1;
    else if (ws_size >= base_bytes + (size_t)E * 128 * 2) mode = 2;
    else                                                  mode = 0;
    float*    msg32 = (float*)   (base + off);
    _Float16* msg16 = (_Float16*)(base + off);

    const int nb = (N + 63) / 64;
    const int eb = (E + 63) / 64;
    const int tb = (E + 255) / 256;

    prep_kernel<<<288, 256, 0, stream>>>(w1, w2, l1w, l2w, lw,
                                         w1f, w2f, l1f, l2f, lwf);
    h_gemm_kernel<<<nb, 256, 0, stream>>>(x, l1f, hbuf, N);

    if (mode == 0) {
        // legacy atomic-scatter path (workspace too small for msg buffer)
        hipMemsetAsync(agg, 0, (size_t)N * 128 * sizeof(float), stream);
        edge_kernel<0><<<eb, 256, 0, stream>>>(ea, ew, ei, ei + E, w1f, w2f, b1, b2,
                                               hbuf, agg, nullptr, nullptr, E);
    } else {
        hipMemsetAsync(offs, 0, (size_t)(N + 1) * sizeof(int), stream);
        hist_kernel<<<tb, 256, 0, stream>>>(ei + E, offs, E);
        scan1_kernel<<<NB, 256, 0, stream>>>(offs, bsum, N);
        scan2_kernel<<<NB, 256, 0, stream>>>(offs, bsum, cur, N, E);
        scatter_kernel<<<tb, 256, 0, stream>>>(ei + E, cur, perm, E);
        if (mode == 1) {
            edge_kernel<1><<<eb, 256, 0, stream>>>(ea, ew, ei, ei + E, w1f, w2f, b1, b2,
                                                   hbuf, nullptr, msg32, nullptr, E);
            gather_kernel<1><<<(N + 3) / 4, 256, 0, stream>>>(msg32, nullptr, offs, perm,
                                                              agg, N);
        } else {
            edge_kernel<2><<<eb, 256, 0, stream>>>(ea, ew, ei, ei + E, w1f, w2f, b1, b2,
                                                   hbuf, nullptr, nullptr, msg16, E);
            gather_kernel<2><<<(N + 3) / 4, 256, 0, stream>>>(nullptr, msg16, offs, perm,
                                                              agg, N);
        }
    }
    fused_out_kernel<<<nb, 256, 0, stream>>>(agg, l2f, l2b, lwf, lb, (float*)d_out, N);
}